// Round 2
// baseline (623.007 us; speedup 1.0000x reference)
//
#include <hip/hip_runtime.h>
#include <hip/hip_bf16.h>

#define NUM_REAL 19
#define NIMG     4
#define T_TOT    76        // NIMG*NUM_REAL
#define V_SEL    131       // 10000 / 76
#define M_ROWS   9956      // T_TOT*V_SEL
#define MP       9984      // padded to 78*128
#define CDIM     256
#define P_PIX    65536
#define NPOS     524       // NIMG*V_SEL (same-class cols incl. self)
#define TILE     128
#define BK       32
#define RPI      2489      // rows per image = 19*131
#define NTILE    3081      // 78*79/2 upper-triangular tiles

typedef __attribute__((ext_vector_type(8))) short short8;
typedef __attribute__((ext_vector_type(4))) float floatx4;

__device__ __forceinline__ void gld_lds16(const unsigned short* g, unsigned short* l) {
    // direct global->LDS, 16B per lane; LDS dest = wave-uniform base + lane*16
    __builtin_amdgcn_global_load_lds((__attribute__((address_space(1))) void*)(g),
                                     (__attribute__((address_space(3))) void*)(l),
                                     16, 0, 0);
}

// ---------------- Kernel 1: per-(image,class) first-V pixel selection ----------------
__global__ __launch_bounds__(512) void k_select(const int* __restrict__ label,
                                                int* __restrict__ sel)
{
    __shared__ int cnts[NUM_REAL * 512];
    const int n   = blockIdx.x;
    const int tid = threadIdx.x;
    for (int k = 0; k < NUM_REAL; ++k) cnts[k * 512 + tid] = 0;
    __syncthreads();
    const int* lab = label + n * 1048576;   // [1024][1024]
    const int p0 = tid * 128;               // 128 dom-pixels per thread, in order
    for (int j = 0; j < 128; ++j) {
        int p = p0 + j;
        int c = lab[((p >> 8) << 12) + ((p & 255) << 2)];  // label[4*r][4*cc]
        cnts[c * 512 + tid]++;
    }
    __syncthreads();
    if (tid < NUM_REAL) {                   // exclusive scan over 512 chunks
        int run = 0, base = tid * 512;
        for (int t2 = 0; t2 < 512; ++t2) {
            int tmp = cnts[base + t2];
            cnts[base + t2] = run;
            run += tmp;
        }
    }
    __syncthreads();
    bool need = false;
    for (int k = 0; k < NUM_REAL; ++k) if (cnts[k * 512 + tid] < V_SEL) need = true;
    if (need) {
        for (int j = 0; j < 128; ++j) {
            int p = p0 + j;
            int c = lab[((p >> 8) << 12) + ((p & 255) << 2)];
            int r = cnts[c * 512 + tid]++;
            if (r < V_SEL) sel[(n * NUM_REAL + c) * V_SEL + r] = p;
        }
    }
}

// ---------------- Kernel 2a: gather -> fp32 Ftmp + norm atomics ----------------
// grid (64 channel-groups, 4 images), 256 thr. Lanes sweep pixels (ascending) so
// addresses spread across HBM channels (fix for 256KB lane-stride aliasing).
__global__ __launch_bounds__(256) void k_gather1(const float* __restrict__ feats,
                                                 const int* __restrict__ sel,
                                                 float* __restrict__ Ftmp,
                                                 float* __restrict__ nrm)
{
    __shared__ int pbuf[RPI];
    const int b  = blockIdx.y;
    const int c0 = blockIdx.x * 4;
    const int tid = threadIdx.x;
    for (int s = tid; s < RPI; s += 256) pbuf[s] = sel[b * RPI + s];
    __syncthreads();
    const float* f0 = feats + (size_t)(b * CDIM + c0) * P_PIX;
    for (int r = tid; r < RPI; r += 256) {
        int p = pbuf[r];
        float x0 = f0[p];
        float x1 = f0[p + P_PIX];
        float x2 = f0[p + 2 * P_PIX];
        float x3 = f0[p + 3 * P_PIX];
        int row = b * RPI + r;
        float4 v = make_float4(x0, x1, x2, x3);
        *reinterpret_cast<float4*>(Ftmp + (size_t)row * CDIM + c0) = v;
        atomicAdd(&nrm[row], x0 * x0 + x1 * x1 + x2 * x2 + x3 * x3);
    }
}

// ---------------- Kernel 2b: normalize -> bf16 F[MP][256] ----------------
__global__ __launch_bounds__(256) void k_gather2(const float* __restrict__ Ftmp,
                                                 const float* __restrict__ nrm,
                                                 unsigned short* __restrict__ F)
{
    const int row = blockIdx.x * 4 + (threadIdx.x >> 6);
    const int c4  = (threadIdx.x & 63) * 4;
    ushort4 o;
    if (row < M_ROWS) {
        float4 v = *reinterpret_cast<const float4*>(Ftmp + (size_t)row * CDIM + c4);
        float rinv = 1.0f / fmaxf(sqrtf(nrm[row]), 1e-12f);
        __hip_bfloat16 h0 = __float2bfloat16(v.x * rinv);
        __hip_bfloat16 h1 = __float2bfloat16(v.y * rinv);
        __hip_bfloat16 h2 = __float2bfloat16(v.z * rinv);
        __hip_bfloat16 h3 = __float2bfloat16(v.w * rinv);
        o.x = *reinterpret_cast<unsigned short*>(&h0);
        o.y = *reinterpret_cast<unsigned short*>(&h1);
        o.z = *reinterpret_cast<unsigned short*>(&h2);
        o.w = *reinterpret_cast<unsigned short*>(&h3);
    } else {
        o.x = o.y = o.z = o.w = 0;
    }
    *reinterpret_cast<ushort4*>(F + (size_t)row * CDIM + c4) = o;
}

// ---------------- Kernel 3: symmetric bf16 MFMA Gram + fused exp-rowsums / pos-store ----------------
__global__ __launch_bounds__(256) void k_gemm(const unsigned short* __restrict__ F,
                                              float* __restrict__ negsum,
                                              float* __restrict__ posst)
{
    __shared__ unsigned short As[TILE * BK];   // pitch 32 shorts = 64B (2-way banks: free)
    __shared__ unsigned short Bs[TILE * BK];

    // decode upper-triangular tile index: f(r) = 78r - r(r-1)/2
    int t = blockIdx.x;
    int bi = (int)((157.0f - sqrtf(24649.0f - 8.0f * (float)t)) * 0.5f);
    if (bi < 0) bi = 0;
    if (bi > 77) bi = 77;
    while ((bi + 1) * 78 - ((bi + 1) * bi) / 2 <= t) ++bi;
    while (bi * 78 - (bi * (bi - 1)) / 2 > t) --bi;
    int bj = bi + (t - (bi * 78 - (bi * (bi - 1)) / 2));
    const bool diag = (bi == bj);
    const int i0 = bi * TILE, j0 = bj * TILE;

    const int tid  = threadIdx.x;
    const int wave = tid >> 6, lane = tid & 63;
    const int qr = lane >> 4, lr = lane & 15;
    const int wr = (wave >> 1) * 64, wc = (wave & 1) * 64;

    floatx4 acc[4][4];
    floatx4 zero4 = {0.f, 0.f, 0.f, 0.f};
    #pragma unroll
    for (int a = 0; a < 4; ++a)
        #pragma unroll
        for (int b = 0; b < 4; ++b) acc[a][b] = zero4;

    // staging: each wave stages 32 rows (2 instrs of 16 rows) per operand
    const int srow = wave * 32 + (lane >> 2);
    const int scol = (lane & 3) * 8;                 // shorts
    const unsigned short* gA = F + (size_t)(i0 + srow) * CDIM + scol;
    const unsigned short* gB = F + (size_t)(j0 + srow) * CDIM + scol;
    unsigned short* lA0 = As + (wave * 32) * BK;
    unsigned short* lA1 = As + (wave * 32 + 16) * BK;
    unsigned short* lB0 = Bs + (wave * 32) * BK;
    unsigned short* lB1 = Bs + (wave * 32 + 16) * BK;

    for (int kc = 0; kc < CDIM; kc += BK) {
        gld_lds16(gA + kc, lA0);
        gld_lds16(gA + kc + 16 * CDIM, lA1);
        gld_lds16(gB + kc, lB0);
        gld_lds16(gB + kc + 16 * CDIM, lB1);
        __syncthreads();
        short8 a[4], b[4];
        #pragma unroll
        for (int mi = 0; mi < 4; ++mi)
            a[mi] = *reinterpret_cast<const short8*>(&As[(wr + mi * 16 + lr) * BK + qr * 8]);
        #pragma unroll
        for (int ni = 0; ni < 4; ++ni)
            b[ni] = *reinterpret_cast<const short8*>(&Bs[(wc + ni * 16 + lr) * BK + qr * 8]);
        #pragma unroll
        for (int mi = 0; mi < 4; ++mi)
            #pragma unroll
            for (int ni = 0; ni < 4; ++ni)
                acc[mi][ni] = __builtin_amdgcn_mfma_f32_16x16x32_bf16(a[mi], b[ni], acc[mi][ni], 0, 0, 0);
        __syncthreads();
    }

    // ---- epilogue: full exp row-sums (and col-sums via symmetry); positives -> posst ----
    int  jcls[4], jpidx[4], gcolv[4];
    bool jval[4];
    #pragma unroll
    for (int ni = 0; ni < 4; ++ni) {
        int gcol = j0 + wc + ni * 16 + lr;
        gcolv[ni] = gcol;
        jval[ni] = gcol < M_ROWS;
        unsigned tj  = (unsigned)gcol / V_SEL;
        unsigned vj  = (unsigned)gcol - tj * V_SEL;
        unsigned bj_ = tj / NUM_REAL;
        jcls[ni]  = (int)(tj - bj_ * NUM_REAL);
        jpidx[ni] = (int)(bj_ * V_SEL + vj);
    }
    float colacc[4] = {0.f, 0.f, 0.f, 0.f};
    #pragma unroll
    for (int mi = 0; mi < 4; ++mi) {
        #pragma unroll
        for (int reg = 0; reg < 4; ++reg) {
            int grow  = i0 + wr + mi * 16 + qr * 4 + reg;
            bool ival = grow < M_ROWS;
            unsigned ti  = (unsigned)grow / V_SEL;
            unsigned vi  = (unsigned)grow - ti * V_SEL;
            unsigned bi_ = ti / NUM_REAL;
            int icls  = (int)(ti - bi_ * NUM_REAL);
            int ipidx = (int)(bi_ * V_SEL + vi);
            float rowacc = 0.f;
            #pragma unroll
            for (int ni = 0; ni < 4; ++ni) {
                float logit = acc[mi][ni][reg] * 2.0f;     // /TEMPERATURE
                bool v = ival && jval[ni];
                float e = v ? __expf(logit) : 0.f;
                rowacc += e;
                colacc[ni] += e;
                if (v && icls == jcls[ni]) {
                    posst[(size_t)grow * NPOS + jpidx[ni]] = logit;
                    if (!diag) posst[(size_t)gcolv[ni] * NPOS + ipidx] = logit;
                }
            }
            rowacc += __shfl_xor(rowacc, 1, 64);
            rowacc += __shfl_xor(rowacc, 2, 64);
            rowacc += __shfl_xor(rowacc, 4, 64);
            rowacc += __shfl_xor(rowacc, 8, 64);
            if (lr == 0 && ival) atomicAdd(&negsum[grow], rowacc);
        }
    }
    if (!diag) {
        #pragma unroll
        for (int ni = 0; ni < 4; ++ni) {
            float c = colacc[ni];
            c += __shfl_xor(c, 16, 64);
            c += __shfl_xor(c, 32, 64);
            if (qr == 0 && jval[ni]) atomicAdd(&negsum[gcolv[ni]], c);
        }
    }
}

// ---------------- Kernel 4: finalize loss ----------------
__global__ __launch_bounds__(128) void k_finalize(const float* __restrict__ posst,
                                                  const float* __restrict__ negsum,
                                                  float* __restrict__ out)
{
    __shared__ float red[4];
    const int row = blockIdx.x;            // < M_ROWS
    const int tid = threadIdx.x;
    unsigned ti = (unsigned)row / V_SEL;
    unsigned vi = (unsigned)row - ti * V_SEL;
    int selfp = (int)((ti / NUM_REAL) * V_SEL + vi);
    const float* pr = posst + (size_t)row * NPOS;

    float l[5], e[5];
    bool val[5];
    float esum = 0.f;
    #pragma unroll
    for (int k = 0; k < 5; ++k) {
        int idx = tid + k * 128;
        val[k] = idx < NPOS;
        l[k] = val[k] ? pr[idx] : 0.f;
        e[k] = val[k] ? __expf(l[k]) : 0.f;
        esum += e[k];
    }
    #pragma unroll
    for (int s = 32; s > 0; s >>= 1) esum += __shfl_xor(esum, s, 64);
    if ((tid & 63) == 0) red[tid >> 6] = esum;
    __syncthreads();
    float ns = negsum[row] - (red[0] + red[1]);   // full rowsum minus same-class exps

    float term = 0.f;
    #pragma unroll
    for (int k = 0; k < 5; ++k) {
        int idx = tid + k * 128;
        if (val[k] && idx != selfp)
            term += l[k] - __logf(e[k] + ns);
    }
    #pragma unroll
    for (int s = 32; s > 0; s >>= 1) term += __shfl_xor(term, s, 64);
    __syncthreads();
    if ((tid & 63) == 0) red[2 + (tid >> 6)] = term;
    __syncthreads();
    if (tid == 0) {
        const float scale = -1.0f / (523.0f * (float)M_ROWS);
        atomicAdd(out, (red[2] + red[3]) * scale);
    }
}

extern "C" void kernel_launch(void* const* d_in, const int* in_sizes, int n_in,
                              void* d_out, int out_size, void* d_ws, size_t ws_size,
                              hipStream_t stream)
{
    const int*   label = (const int*)d_in[0];
    const float* feats = (const float*)d_in[1];
    float*       out   = (float*)d_out;

    char* ws = (char*)d_ws;
    unsigned short* F = (unsigned short*)ws;                    // MP*CDIM*2 = 5,111,808 B
    size_t off = (size_t)MP * CDIM * 2;
    int* sel = (int*)(ws + off);
    off += (size_t)T_TOT * V_SEL * 4;
    off = (off + 255) & ~(size_t)255;
    float* negsum = (float*)(ws + off);                         // MP floats
    off += (size_t)MP * 4;
    float* nrm = (float*)(ws + off);                            // MP floats (adjacent: one memset)
    off += (size_t)MP * 4;
    off = (off + 255) & ~(size_t)255;
    float* posst = (float*)(ws + off);                          // M_ROWS*NPOS*4 ≈ 20.9 MB
    float* Ftmp  = (float*)(ws + off);                          // aliases posst (dead before k_gemm)

    hipMemsetAsync(sel, 0, (size_t)T_TOT * V_SEL * 4, stream);
    hipMemsetAsync(negsum, 0, (size_t)MP * 8, stream);          // negsum + nrm
    hipMemsetAsync(out, 0, sizeof(float), stream);

    k_select<<<NIMG, 512, 0, stream>>>(label, sel);
    dim3 g1(CDIM / 4, NIMG);
    k_gather1<<<g1, 256, 0, stream>>>(feats, sel, Ftmp, nrm);
    k_gather2<<<MP / 4, 256, 0, stream>>>(Ftmp, nrm, F);
    k_gemm<<<NTILE, 256, 0, stream>>>(F, negsum, posst);
    k_finalize<<<M_ROWS, 128, 0, stream>>>(posst, negsum, out);
}

// Round 3
// 433.287 us; speedup vs baseline: 1.4379x; 1.4379x over previous
//
#include <hip/hip_runtime.h>
#include <hip/hip_bf16.h>

#define NUM_REAL 19
#define NIMG     4
#define T_TOT    76        // NIMG*NUM_REAL
#define V_SEL    131       // 10000 / 76
#define M_ROWS   9956      // T_TOT*V_SEL
#define MP       9984      // padded to 78*128
#define CDIM     256
#define P_PIX    65536
#define TILE     128
#define BK       32
#define RPI      2489      // rows per image = 19*131
#define NT1      3081      // 78*79/2 upper-triangular tiles
#define NCHUNK   32        // label chunks per image
#define CHPIX    2048      // dom pixels per chunk
#define CT       5         // 128-row tiles per 524-row class block
#define NT2      (NUM_REAL * 15)   // 19 classes * C(5+1,2) upper tiles

typedef __attribute__((ext_vector_type(8))) short short8;
typedef __attribute__((ext_vector_type(4))) float floatx4;

__device__ __forceinline__ void gld_lds16(const unsigned short* g, unsigned short* l) {
    // direct global->LDS, 16B per lane; LDS dest = wave-uniform base + lane*16
    __builtin_amdgcn_global_load_lds((__attribute__((address_space(1))) void*)(g),
                                     (__attribute__((address_space(3))) void*)(l),
                                     16, 0, 0);
}

// ---------------- Kernel 1a: per-chunk class histograms ----------------
__global__ __launch_bounds__(256) void k_hist(const int* __restrict__ label,
                                              int* __restrict__ ghist)
{
    __shared__ int h[NUM_REAL];
    const int img = blockIdx.y, ch = blockIdx.x, tid = threadIdx.x;
    if (tid < NUM_REAL) h[tid] = 0;
    __syncthreads();
    const int* lab = label + img * 1048576;
    const int p0 = ch * CHPIX + tid * 8;
    #pragma unroll
    for (int j = 0; j < 8; ++j) {
        int p = p0 + j;
        int c = lab[((p >> 8) << 12) + ((p & 255) << 2)];
        atomicAdd(&h[c], 1);
    }
    __syncthreads();
    if (tid < NUM_REAL) ghist[(img * NCHUNK + ch) * NUM_REAL + tid] = h[tid];
}

// ---------------- Kernel 1b: ordered scatter of first-131 pixels per class ----------------
__global__ __launch_bounds__(256) void k_scatter(const int* __restrict__ label,
                                                 const int* __restrict__ ghist,
                                                 int* __restrict__ sel)
{
    __shared__ int cnt[NUM_REAL * 256];
    const int img = blockIdx.y, ch = blockIdx.x, tid = threadIdx.x;
    #pragma unroll
    for (int k = 0; k < NUM_REAL; ++k) cnt[k * 256 + tid] = 0;   // own slots only
    __shared__ int base[NUM_REAL];
    if (tid < NUM_REAL) {
        int b = 0;
        for (int q = 0; q < ch; ++q) b += ghist[(img * NCHUNK + q) * NUM_REAL + tid];
        base[tid] = b;
    }
    const int* lab = label + img * 1048576;
    const int p0 = ch * CHPIX + tid * 8;
    #pragma unroll
    for (int j = 0; j < 8; ++j) {
        int p = p0 + j;
        int c = lab[((p >> 8) << 12) + ((p & 255) << 2)];
        cnt[c * 256 + tid]++;
    }
    __syncthreads();
    if (tid < NUM_REAL) {                    // exclusive scan over 256 threads, seeded by base
        int run = base[tid], bb = tid * 256;
        for (int t2 = 0; t2 < 256; ++t2) {
            int tmp = cnt[bb + t2];
            cnt[bb + t2] = run;
            run += tmp;
        }
    }
    __syncthreads();
    bool need = false;
    #pragma unroll
    for (int k = 0; k < NUM_REAL; ++k) if (cnt[k * 256 + tid] < V_SEL) need = true;
    if (need) {
        for (int j = 0; j < 8; ++j) {
            int p = p0 + j;
            int c = lab[((p >> 8) << 12) + ((p & 255) << 2)];
            int r = cnt[c * 256 + tid]++;
            if (r < V_SEL) sel[(img * NUM_REAL + c) * V_SEL + r] = p;
        }
    }
}

// ---------------- Kernel 2a: gather -> fp32 Ftmp + norm atomics ----------------
__global__ __launch_bounds__(256) void k_gather1(const float* __restrict__ feats,
                                                 const int* __restrict__ sel,
                                                 float* __restrict__ Ftmp,
                                                 float* __restrict__ nrm)
{
    __shared__ int pbuf[RPI];
    const int b  = blockIdx.y;
    const int c0 = blockIdx.x * 4;
    const int tid = threadIdx.x;
    for (int s = tid; s < RPI; s += 256) pbuf[s] = sel[b * RPI + s];
    __syncthreads();
    const float* f0 = feats + (size_t)(b * CDIM + c0) * P_PIX;
    for (int r = tid; r < RPI; r += 256) {
        int p = pbuf[r];
        float x0 = f0[p];
        float x1 = f0[p + P_PIX];
        float x2 = f0[p + 2 * P_PIX];
        float x3 = f0[p + 3 * P_PIX];
        int row = b * RPI + r;
        float4 v = make_float4(x0, x1, x2, x3);
        *reinterpret_cast<float4*>(Ftmp + (size_t)row * CDIM + c0) = v;
        atomicAdd(&nrm[row], x0 * x0 + x1 * x1 + x2 * x2 + x3 * x3);
    }
}

// ---------------- Kernel 2b: normalize -> bf16 F[MP][256] ----------------
__global__ __launch_bounds__(256) void k_gather2(const float* __restrict__ Ftmp,
                                                 const float* __restrict__ nrm,
                                                 unsigned short* __restrict__ F)
{
    const int row = blockIdx.x * 4 + (threadIdx.x >> 6);
    const int c4  = (threadIdx.x & 63) * 4;
    ushort4 o;
    if (row < M_ROWS) {
        float4 v = *reinterpret_cast<const float4*>(Ftmp + (size_t)row * CDIM + c4);
        float rinv = 1.0f / fmaxf(sqrtf(nrm[row]), 1e-12f);
        __hip_bfloat16 h0 = __float2bfloat16(v.x * rinv);
        __hip_bfloat16 h1 = __float2bfloat16(v.y * rinv);
        __hip_bfloat16 h2 = __float2bfloat16(v.z * rinv);
        __hip_bfloat16 h3 = __float2bfloat16(v.w * rinv);
        o.x = *reinterpret_cast<unsigned short*>(&h0);
        o.y = *reinterpret_cast<unsigned short*>(&h1);
        o.z = *reinterpret_cast<unsigned short*>(&h2);
        o.w = *reinterpret_cast<unsigned short*>(&h3);
    } else {
        o.x = o.y = o.z = o.w = 0;
    }
    *reinterpret_cast<ushort4*>(F + (size_t)row * CDIM + c4) = o;
}

// ---------------- Kernel 3: symmetric Gram, fused different-class exp sums -> negsum ----------------
__global__ __launch_bounds__(256) void k_gemm(const unsigned short* __restrict__ F,
                                              float* __restrict__ negsum)
{
    __shared__ unsigned short As[2][TILE * BK];
    __shared__ unsigned short Bs[2][TILE * BK];

    int t = blockIdx.x;                      // upper-triangular tile decode
    int bi = (int)((157.0f - sqrtf(24649.0f - 8.0f * (float)t)) * 0.5f);
    if (bi < 0) bi = 0;
    if (bi > 77) bi = 77;
    while ((bi + 1) * 78 - ((bi + 1) * bi) / 2 <= t) ++bi;
    while (bi * 78 - (bi * (bi - 1)) / 2 > t) --bi;
    int bj = bi + (t - (bi * 78 - (bi * (bi - 1)) / 2));
    const bool diag = (bi == bj);
    const int i0 = bi * TILE, j0 = bj * TILE;

    const int tid  = threadIdx.x;
    const int wave = tid >> 6, lane = tid & 63;
    const int qr = lane >> 4, lr = lane & 15;
    const int wr = (wave >> 1) * 64, wc = (wave & 1) * 64;

    floatx4 acc[4][4];
    floatx4 zero4 = {0.f, 0.f, 0.f, 0.f};
    #pragma unroll
    for (int a = 0; a < 4; ++a)
        #pragma unroll
        for (int b = 0; b < 4; ++b) acc[a][b] = zero4;

    const int srow = wave * 32 + (lane >> 2);
    const int scol = (lane & 3) * 8;
    const unsigned short* gA = F + (size_t)(i0 + srow) * CDIM + scol;
    const unsigned short* gB = F + (size_t)(j0 + srow) * CDIM + scol;
    const int l0 = (wave * 32) * BK, l1 = (wave * 32 + 16) * BK;

    gld_lds16(gA,             &As[0][l0]);
    gld_lds16(gA + 16 * CDIM, &As[0][l1]);
    gld_lds16(gB,             &Bs[0][l0]);
    gld_lds16(gB + 16 * CDIM, &Bs[0][l1]);

    #pragma unroll 2
    for (int k = 0; k < 8; ++k) {
        __syncthreads();                      // staging of buf[k&1] now visible
        const int cur = k & 1, nxt = cur ^ 1;
        if (k < 7) {                          // prefetch next chunk; drains at NEXT barrier
            const int kc = (k + 1) * BK;
            gld_lds16(gA + kc,             &As[nxt][l0]);
            gld_lds16(gA + kc + 16 * CDIM, &As[nxt][l1]);
            gld_lds16(gB + kc,             &Bs[nxt][l0]);
            gld_lds16(gB + kc + 16 * CDIM, &Bs[nxt][l1]);
        }
        short8 a[4], b[4];
        #pragma unroll
        for (int mi = 0; mi < 4; ++mi)
            a[mi] = *reinterpret_cast<const short8*>(&As[cur][(wr + mi * 16 + lr) * BK + qr * 8]);
        #pragma unroll
        for (int ni = 0; ni < 4; ++ni)
            b[ni] = *reinterpret_cast<const short8*>(&Bs[cur][(wc + ni * 16 + lr) * BK + qr * 8]);
        #pragma unroll
        for (int mi = 0; mi < 4; ++mi)
            #pragma unroll
            for (int ni = 0; ni < 4; ++ni)
                acc[mi][ni] = __builtin_amdgcn_mfma_f32_16x16x32_bf16(a[mi], b[ni], acc[mi][ni], 0, 0, 0);
    }

    // ---- epilogue: ns partial sums (different-class exp), LDS-staged, 256 atomics/tile ----
    int jcls[4];
    bool jval[4];
    #pragma unroll
    for (int ni = 0; ni < 4; ++ni) {
        int gcol = j0 + wc + ni * 16 + lr;
        jval[ni] = gcol < M_ROWS;
        unsigned tj = (unsigned)gcol / V_SEL;
        jcls[ni] = (int)(tj - (tj / NUM_REAL) * NUM_REAL);
    }
    float* red  = (float*)&As[0][0];   // [128][2] row partials (col-half per slot)
    float* cred = (float*)&Bs[0][0];   // [128][2] col partials (row-half per slot)
    float colacc[4] = {0.f, 0.f, 0.f, 0.f};
    #pragma unroll
    for (int mi = 0; mi < 4; ++mi) {
        #pragma unroll
        for (int reg = 0; reg < 4; ++reg) {
            int rloc = wr + mi * 16 + qr * 4 + reg;
            int grow = i0 + rloc;
            bool ival = grow < M_ROWS;
            unsigned ti = (unsigned)grow / V_SEL;
            int icls = (int)(ti - (ti / NUM_REAL) * NUM_REAL);
            float rowacc = 0.f;
            #pragma unroll
            for (int ni = 0; ni < 4; ++ni) {
                bool v = ival && jval[ni] && (icls != jcls[ni]);
                float e = v ? __expf(acc[mi][ni][reg] * 2.0f) : 0.f;
                rowacc += e;
                colacc[ni] += e;
            }
            rowacc += __shfl_xor(rowacc, 1, 64);
            rowacc += __shfl_xor(rowacc, 2, 64);
            rowacc += __shfl_xor(rowacc, 4, 64);
            rowacc += __shfl_xor(rowacc, 8, 64);
            if (lr == 0) red[rloc * 2 + (wave & 1)] = rowacc;
        }
    }
    #pragma unroll
    for (int ni = 0; ni < 4; ++ni) {
        float cc = colacc[ni];
        cc += __shfl_xor(cc, 16, 64);
        cc += __shfl_xor(cc, 32, 64);
        if (qr == 0) cred[(wc + ni * 16 + lr) * 2 + (wave >> 1)] = cc;
    }
    __syncthreads();
    if (tid < 128) {
        int row = i0 + tid;
        if (row < M_ROWS) atomicAdd(&negsum[row], red[tid * 2] + red[tid * 2 + 1]);
    } else {
        int cc2 = tid - 128, col = j0 + cc2;
        if (!diag && col < M_ROWS) atomicAdd(&negsum[col], cred[cc2 * 2] + cred[cc2 * 2 + 1]);
    }
}

// ---------------- Kernel 4: same-class Gram tiles -> positive loss terms ----------------
__global__ __launch_bounds__(256) void k_pos(const unsigned short* __restrict__ F,
                                             const float* __restrict__ negsum,
                                             float* __restrict__ out)
{
    __shared__ unsigned short As[2][TILE * BK];
    __shared__ unsigned short Bs[2][TILE * BK];
    __shared__ float wred[4];

    const int c = blockIdx.x / 15;
    int pidx = blockIdx.x % 15;
    int ti = 0;
    while (pidx >= CT - ti) { pidx -= CT - ti; ++ti; }
    const int tj = ti + pidx;
    const int u0i = ti * TILE, u0j = tj * TILE;
    const bool offd = (ti != tj);

    const int tid  = threadIdx.x;
    const int wave = tid >> 6, lane = tid & 63;
    const int qr = lane >> 4, lr = lane & 15;
    const int wr = (wave >> 1) * 64, wc = (wave & 1) * 64;

    floatx4 acc[4][4];
    floatx4 zero4 = {0.f, 0.f, 0.f, 0.f};
    #pragma unroll
    for (int a = 0; a < 4; ++a)
        #pragma unroll
        for (int b = 0; b < 4; ++b) acc[a][b] = zero4;

    const int srow = wave * 32 + (lane >> 2);
    const int scol = (lane & 3) * 8;
    auto growmap = [&](int u) -> int {
        int uc = u < 524 ? u : 523;
        int b = uc / 131, v = uc - 131 * b;
        return b * RPI + c * V_SEL + v;
    };
    const unsigned short* gA0 = F + (size_t)growmap(u0i + srow) * CDIM + scol;
    const unsigned short* gA1 = F + (size_t)growmap(u0i + srow + 16) * CDIM + scol;
    const unsigned short* gB0 = F + (size_t)growmap(u0j + srow) * CDIM + scol;
    const unsigned short* gB1 = F + (size_t)growmap(u0j + srow + 16) * CDIM + scol;
    const int l0 = (wave * 32) * BK, l1 = (wave * 32 + 16) * BK;

    gld_lds16(gA0, &As[0][l0]);
    gld_lds16(gA1, &As[0][l1]);
    gld_lds16(gB0, &Bs[0][l0]);
    gld_lds16(gB1, &Bs[0][l1]);

    #pragma unroll 2
    for (int k = 0; k < 8; ++k) {
        __syncthreads();
        const int cur = k & 1, nxt = cur ^ 1;
        if (k < 7) {
            const int kc = (k + 1) * BK;
            gld_lds16(gA0 + kc, &As[nxt][l0]);
            gld_lds16(gA1 + kc, &As[nxt][l1]);
            gld_lds16(gB0 + kc, &Bs[nxt][l0]);
            gld_lds16(gB1 + kc, &Bs[nxt][l1]);
        }
        short8 a[4], b[4];
        #pragma unroll
        for (int mi = 0; mi < 4; ++mi)
            a[mi] = *reinterpret_cast<const short8*>(&As[cur][(wr + mi * 16 + lr) * BK + qr * 8]);
        #pragma unroll
        for (int ni = 0; ni < 4; ++ni)
            b[ni] = *reinterpret_cast<const short8*>(&Bs[cur][(wc + ni * 16 + lr) * BK + qr * 8]);
        #pragma unroll
        for (int mi = 0; mi < 4; ++mi)
            #pragma unroll
            for (int ni = 0; ni < 4; ++ni)
                acc[mi][ni] = __builtin_amdgcn_mfma_f32_16x16x32_bf16(a[mi], b[ni], acc[mi][ni], 0, 0, 0);
    }

    int  ujv[4];
    bool jval[4];
    float nsj[4];
    #pragma unroll
    for (int ni = 0; ni < 4; ++ni) {
        int uj = u0j + wc + ni * 16 + lr;
        ujv[ni] = uj;
        jval[ni] = uj < 524;
        nsj[ni] = jval[ni] ? negsum[growmap(uj)] : 0.f;
    }
    float tsum = 0.f;
    #pragma unroll
    for (int mi = 0; mi < 4; ++mi) {
        #pragma unroll
        for (int reg = 0; reg < 4; ++reg) {
            int ui = u0i + wr + mi * 16 + qr * 4 + reg;
            bool ival = ui < 524;
            float nsi = ival ? negsum[growmap(ui)] : 0.f;
            #pragma unroll
            for (int ni = 0; ni < 4; ++ni) {
                if (ival && jval[ni] && ui != ujv[ni]) {
                    float l  = acc[mi][ni][reg] * 2.0f;
                    float el = __expf(l);
                    tsum += l - __logf(el + nsi);
                    if (offd) tsum += l - __logf(el + nsj[ni]);
                }
            }
        }
    }
    #pragma unroll
    for (int s = 32; s > 0; s >>= 1) tsum += __shfl_xor(tsum, s, 64);
    if (lane == 0) wred[wave] = tsum;
    __syncthreads();
    if (tid == 0) {
        const float scale = -1.0f / (523.0f * (float)M_ROWS);
        atomicAdd(out, (wred[0] + wred[1] + wred[2] + wred[3]) * scale);
    }
}

extern "C" void kernel_launch(void* const* d_in, const int* in_sizes, int n_in,
                              void* d_out, int out_size, void* d_ws, size_t ws_size,
                              hipStream_t stream)
{
    const int*   label = (const int*)d_in[0];
    const float* feats = (const float*)d_in[1];
    float*       out   = (float*)d_out;

    char* ws = (char*)d_ws;
    unsigned short* F = (unsigned short*)ws;                    // MP*CDIM*2 = 5,111,808 B
    size_t off = (size_t)MP * CDIM * 2;
    int* sel = (int*)(ws + off);
    off += (size_t)T_TOT * V_SEL * 4;
    off = (off + 255) & ~(size_t)255;
    float* negsum = (float*)(ws + off);                         // MP floats (39936 B, 256-mult)
    off += (size_t)MP * 4;
    float* nrm = (float*)(ws + off);                            // MP floats, contiguous w/ negsum
    off += (size_t)MP * 4;
    int* ghist = (int*)(ws + off);                              // 4*32*19 ints
    off += (size_t)NIMG * NCHUNK * NUM_REAL * 4;
    off = (off + 255) & ~(size_t)255;
    float* Ftmp = (float*)(ws + off);                           // MP*CDIM*4 ≈ 10.2 MB

    hipMemsetAsync(negsum, 0, (size_t)MP * 8, stream);          // negsum + nrm
    hipMemsetAsync(out, 0, sizeof(float), stream);

    dim3 gh(NCHUNK, NIMG);
    k_hist<<<gh, 256, 0, stream>>>(label, ghist);
    k_scatter<<<gh, 256, 0, stream>>>(label, ghist, sel);
    dim3 g1(CDIM / 4, NIMG);
    k_gather1<<<g1, 256, 0, stream>>>(feats, sel, Ftmp, nrm);
    k_gather2<<<MP / 4, 256, 0, stream>>>(Ftmp, nrm, F);
    k_gemm<<<NT1, 256, 0, stream>>>(F, negsum);
    k_pos<<<NT2, 256, 0, stream>>>(F, negsum, out);
}